// Round 1
// baseline (108.723 us; speedup 1.0000x reference)
//
#include <hip/hip_runtime.h>

typedef float f4 __attribute__((ext_vector_type(4)));

constexpr int N_  = 4;
constexpr int C_  = 320;
constexpr int H_  = 80;
constexpr int W_  = 160;
constexpr int G_  = 40;
constexpr int CPG = 8;     // channels per group
constexpr int D_  = 48;    // max disparity
constexpr int PAD = 48;    // zero pad in front of R rows (covers w-d >= -47)
constexpr int RW  = PAD + W_;            // 208 floats per R row
constexpr int TILES = (W_ / 4) * (D_ / 4); // 40*12 = 480 4x4 tiles per block

__global__ __launch_bounds__(256) void gw_cost_kernel(const float* __restrict__ Lg,
                                                      const float* __restrict__ Rg,
                                                      float* __restrict__ out) {
    __shared__ float Ls[CPG][W_];   // 8 x 160
    __shared__ float Rs[CPG][RW];   // 8 x 208, first 48 floats are zero

    const int blk = blockIdx.x;               // ((n*G + g)*H + h)
    const int h = blk % H_;
    const int g = (blk / H_) % G_;
    const int n = blk / (H_ * G_);

    const int tid = threadIdx.x;

    // ---- stage global -> LDS (f32x4, all 16B-aligned: row bases are x160 floats) ----
    for (int i = tid; i < CPG * (W_ / 4); i += 256) {   // 320 float4 per input
        const int ci = i / (W_ / 4);
        const int w4 = i % (W_ / 4);
        const size_t gb = ((size_t)(n * C_ + g * CPG + ci) * H_ + h) * W_;
        *(f4*)&Ls[ci][w4 * 4]       = *(const f4*)(Lg + gb + w4 * 4);
        *(f4*)&Rs[ci][PAD + w4 * 4] = *(const f4*)(Rg + gb + w4 * 4);
    }
    for (int i = tid; i < CPG * (PAD / 4); i += 256) {  // 96 float4 of zeros
        const int ci = i / (PAD / 4);
        const int p4 = i % (PAD / 4);
        *(f4*)&Rs[ci][p4 * 4] = (f4)(0.0f);
    }
    __syncthreads();

    const size_t ob = (size_t)blk * (W_ * D_);

    // ---- compute: each thread owns 4w x 4d tiles; td is the fast tile coord ----
    for (int t = tid; t < TILES; t += 256) {
        const int tw = t / (D_ / 4);
        const int td = t % (D_ / 4);
        const int w0 = tw * 4;
        const int d0 = td * 4;
        const int r0 = w0 - d0 + PAD;   // in [4, 204]; reads at r0-4 .. r0+3 stay in [0, 207]

        f4 acc0 = (f4)(0.0f);
        f4 acc1 = (f4)(0.0f);
        f4 acc2 = (f4)(0.0f);
        f4 acc3 = (f4)(0.0f);

        #pragma unroll
        for (int c = 0; c < CPG; ++c) {
            const f4 lv = *(const f4*)&Ls[c][w0];       // L[c][w0..w0+3]
            const f4 ra = *(const f4*)&Rs[c][r0 - 4];   // R[c][r0-4..r0-1]
            const f4 rb = *(const f4*)&Rs[c][r0];       // R[c][r0..r0+3]
            float rr[8];
            #pragma unroll
            for (int k = 0; k < 4; ++k) { rr[k] = ra[k]; rr[k + 4] = rb[k]; }
            // out(w0+i, d0+j) needs R[c][r0 + i - j]  -> rr[4 + i - j]
            #pragma unroll
            for (int j = 0; j < 4; ++j) {
                acc0[j] += lv[0] * rr[4 + 0 - j];
                acc1[j] += lv[1] * rr[4 + 1 - j];
                acc2[j] += lv[2] * rr[4 + 2 - j];
                acc3[j] += lv[3] * rr[4 + 3 - j];
            }
        }

        float* op = out + ob + (size_t)w0 * D_ + d0;
        *(f4*)(op + 0 * D_) = acc0 * 0.125f;
        *(f4*)(op + 1 * D_) = acc1 * 0.125f;
        *(f4*)(op + 2 * D_) = acc2 * 0.125f;
        *(f4*)(op + 3 * D_) = acc3 * 0.125f;
    }
}

extern "C" void kernel_launch(void* const* d_in, const int* in_sizes, int n_in,
                              void* d_out, int out_size, void* d_ws, size_t ws_size,
                              hipStream_t stream) {
    const float* Lg = (const float*)d_in[0];
    const float* Rg = (const float*)d_in[1];
    float* out = (float*)d_out;

    const int nblocks = N_ * G_ * H_;   // 12800 blocks, one per (n, g, h)
    gw_cost_kernel<<<dim3(nblocks), dim3(256), 0, stream>>>(Lg, Rg, out);
}